// Round 2
// baseline (129.081 us; speedup 1.0000x reference)
//
#include <hip/hip_runtime.h>

#define GD    256
#define DIM   64
#define KCB   1024
#define KT    256   // codewords per LDS tile
#define NROW  32768
#define NTOT  131072

typedef float floatx4 __attribute__((ext_vector_type(4)));
typedef __bf16 bf16x8 __attribute__((ext_vector_type(8)));
typedef unsigned int uint;

union ABu { bf16x8 v; __bf16 h[8]; uint4 u4; };
union P8u { __bf16 h[8]; uint4 u4; };

// ---------------------------------------------------------------------------
// Prep: latents fp32 -> bf16 rows [g][n][64] (plain layout) + x_sq;
// codebook fp32 -> bf16 rows with 16B-chunk XOR swizzle (LDS image) + initv;
// loss = 0. Pure-BW kernel; all conversion VALU lives here.
// (keys init removed: score now plain-stores keys, no atomicMin seed needed)
// ---------------------------------------------------------------------------
extern "C" __global__ void __launch_bounds__(256)
vq_prep(const float* __restrict__ latents, const float* __restrict__ cbg,
        uint* __restrict__ lat_bf, uint* __restrict__ cb_bf,
        float* __restrict__ initv, float* __restrict__ xsq_g,
        float* __restrict__ loss)
{
    const int bid = blockIdx.x;
    const int tid = threadIdx.x;
    if (bid < 512) {                          // latents: thread = one (g,n) row
        const int g = tid >> 6;               // wave-uniform group
        const int n = bid * 64 + (tid & 63);
        const float4* __restrict__ src = (const float4*)latents + (size_t)n * 64 + g * 16;
        uint* __restrict__ drow = lat_bf + ((size_t)g * NROW + n) * 32;
        float xp = 0.f;
        #pragma unroll
        for (int c = 0; c < 8; ++c) {
            const float4 f0 = src[c * 2];
            const float4 f1 = src[c * 2 + 1];
            xp += f0.x*f0.x + f0.y*f0.y + f0.z*f0.z + f0.w*f0.w
                + f1.x*f1.x + f1.y*f1.y + f1.z*f1.z + f1.w*f1.w;
            P8u t;
            t.h[0]=(__bf16)f0.x; t.h[1]=(__bf16)f0.y; t.h[2]=(__bf16)f0.z; t.h[3]=(__bf16)f0.w;
            t.h[4]=(__bf16)f1.x; t.h[5]=(__bf16)f1.y; t.h[6]=(__bf16)f1.z; t.h[7]=(__bf16)f1.w;
            *(uint4*)&drow[c * 4] = t.u4;     // plain chunk order (global reads)
        }
        xsq_g[g * NROW + n] = xp;
        if (bid == 0 && tid == 0) *loss = 0.f;
    } else {                                  // codebook: thread = one codeword
        const int k = (bid - 512) * 256 + tid;          // 0..4095 global row
        const float4* __restrict__ src = (const float4*)cbg + (size_t)k * 16;
        uint* __restrict__ drow = cb_bf + (size_t)k * 32;
        float csq = 0.f;
        #pragma unroll
        for (int c = 0; c < 8; ++c) {
            const float4 f0 = src[c * 2];
            const float4 f1 = src[c * 2 + 1];
            csq += f0.x*f0.x + f0.y*f0.y + f0.z*f0.z + f0.w*f0.w
                 + f1.x*f1.x + f1.y*f1.y + f1.z*f1.z + f1.w*f1.w;
            P8u t;
            t.h[0]=(__bf16)f0.x; t.h[1]=(__bf16)f0.y; t.h[2]=(__bf16)f0.z; t.h[3]=(__bf16)f0.w;
            t.h[4]=(__bf16)f1.x; t.h[5]=(__bf16)f1.y; t.h[6]=(__bf16)f1.z; t.h[7]=(__bf16)f1.w;
            const int dc = c ^ (k & 7);       // LDS-bank XOR swizzle baked in
            *(uint4*)&drow[dc * 4] = t.u4;
        }
        initv[k] = -0.5f * csq - 0.5f;        // makes every score < 0
    }
}

// ---------------------------------------------------------------------------
// Score: single-pass over all 4 codebook tiles per block.
// 512 blocks = chunk(7b) | g(2b): one block owns 256 rows x full K=1024.
// Double-buffered 2x32KB tile DMA (global_load_lds) issued BEFORE compute of
// the current tile; the per-tile __syncthreads (vmcnt drain) lands after 16
// MFMA t-iters -> DMA hidden. best accumulates across tiles in registers ->
// plain keys store (atomicMin + keys-init eliminated, lat_bf read 1x not 4x).
// LDS 68 KB -> 2 blocks/CU (grid = exactly 2/CU, one pass, no tail).
// ---------------------------------------------------------------------------
extern "C" __global__ void __launch_bounds__(256, 2)
vq_score(const uint* __restrict__ lat_bf, const uint* __restrict__ cb_bf,
         const float* __restrict__ initv, uint* __restrict__ keys)
{
    __shared__ __attribute__((aligned(16))) uint  cb_lds[2][KT * 32]; // 2x32 KB
    __shared__ __attribute__((aligned(16))) float iv_lds[KCB];        // 4 KB

    const int tid  = threadIdx.x;
    const int wave = tid >> 6;
    const int lane = tid & 63;
    const int l15  = lane & 15;
    const int quad = lane >> 4;

    const int bid   = blockIdx.x;
    const int chunk = bid & 127;              // bid%8 spreads chunks over XCDs
    const int g     = bid >> 7;
    const int wRow0 = chunk * 256 + wave * 64;

    const uint* gcb = cb_bf + (size_t)g * (KCB * 32);

    // ---- prologue: DMA tile0 + all 4 KB of initv; A-frag loads overlap ----
    {
        #pragma unroll
        for (int i = 0; i < 8; ++i) {
            const int off = wave * 2048 + i * 256;          // uint words
            __builtin_amdgcn_global_load_lds(
                (const __attribute__((address_space(1))) uint*)(gcb + off + lane * 4),
                (__attribute__((address_space(3))) uint*)&cb_lds[0][off], 16, 0, 0);
        }
        const uint* isrc = (const uint*)(initv + g * KCB) + wave * 256;
        __builtin_amdgcn_global_load_lds(
            (const __attribute__((address_space(1))) uint*)(isrc + lane * 4),
            (__attribute__((address_space(3))) uint*)&iv_lds[wave * 256], 16, 0, 0);
    }

    // ---- A fragments: direct bf16 16B loads (read exactly once now) ----
    bf16x8 afrag[4][2];
    const uint* abase = lat_bf + ((size_t)g * NROW + wRow0) * 32;
    #pragma unroll
    for (int rt = 0; rt < 4; ++rt)
        #pragma unroll
        for (int ks = 0; ks < 2; ++ks) {
            ABu a;
            a.u4 = *(const uint4*)&abase[(rt * 16 + l15) * 32 + (ks * 4 + quad) * 4];
            afrag[rt][ks] = a.v;
        }
    __syncthreads();                          // tile0 + iv + afrag all ready

    uint best[4][4];
    #pragma unroll
    for (int rt = 0; rt < 4; ++rt)
        #pragma unroll
        for (int r = 0; r < 4; ++r) best[rt][r] = 0xFFFFFFFFu;

    const int o0   = l15 * 32;
    const int sw0  = (quad       ^ (l15 & 7)) << 2;
    const int sw1  = ((quad + 4) ^ (l15 & 7)) << 2;

    #pragma unroll
    for (int tile = 0; tile < 4; ++tile) {    // compile-time tile (full unroll)
        // issue next tile's DMA first: overlaps the 16 t-iters below
        if (tile < 3) {
            const uint* gsrc = gcb + (tile + 1) * (KT * 32);
            #pragma unroll
            for (int i = 0; i < 8; ++i) {
                const int off = wave * 2048 + i * 256;
                __builtin_amdgcn_global_load_lds(
                    (const __attribute__((address_space(1))) uint*)(gsrc + off + lane * 4),
                    (__attribute__((address_space(3))) uint*)&cb_lds[(tile + 1) & 1][off], 16, 0, 0);
            }
        }

        const uint*  bbase0 = &cb_lds[tile & 1][o0 + sw0];
        const uint*  bbase1 = &cb_lds[tile & 1][o0 + sw1];
        const float* ivb    = &iv_lds[tile * KT + l15];
        const uint   kcol0  = (uint)(tile * KT + l15);

        #pragma unroll 4
        for (int t = 0; t < 16; ++t) {
            const float v = ivb[t * 16];
            ABu b0, b1;
            b0.u4 = *(const uint4*)(bbase0 + t * 512);
            b1.u4 = *(const uint4*)(bbase1 + t * 512);
            const uint kcol = kcol0 + t * 16;
            const floatx4 accb = { v, v, v, v };   // shared C operand (D != C)
            #pragma unroll
            for (int rt = 0; rt < 4; ++rt) {
                floatx4 acc = __builtin_amdgcn_mfma_f32_16x16x32_bf16(afrag[rt][0], b0.v, accb, 0, 0, 0);
                acc = __builtin_amdgcn_mfma_f32_16x16x32_bf16(afrag[rt][1], b1.v, acc, 0, 0, 0);
                // score < 0 -> fp32 bits monotone decreasing; pack idx, min_u32
                #pragma unroll
                for (int r = 0; r < 4; ++r) {
                    const uint key = (__float_as_uint(acc[r]) & 0xFFFFFC00u) | kcol;
                    best[rt][r] = best[rt][r] < key ? best[rt][r] : key;
                }
            }
        }
        if (tile < 3) __syncthreads();        // drains next-tile DMA (vmcnt) +
                                              // frees buf[tile&1] for tile+2
    }

    // ---- 16-lane column reduce, plain store (block owns its rows) ----
    #pragma unroll
    for (int rt = 0; rt < 4; ++rt)
        #pragma unroll
        for (int r = 0; r < 4; ++r) {
            uint kmin = best[rt][r];
            #pragma unroll
            for (int m = 1; m <= 8; m <<= 1) {
                const uint o = (uint)__shfl_xor((int)kmin, m);
                kmin = o < kmin ? o : kmin;
            }
            if (l15 == 0)
                keys[g * NROW + wRow0 + rt * 16 + quad * 4 + r] = kmin;
        }
}

// ---------------------------------------------------------------------------
// Emit: wave = 16 rows x 4 groups (quad=group); dense 1 KB row writes.
// ---------------------------------------------------------------------------
extern "C" __global__ void __launch_bounds__(256, 4)
vq_emit(const uint* __restrict__ keys, const float* __restrict__ xsq_g,
        const float* __restrict__ cbg, float* __restrict__ out,
        float* __restrict__ loss)
{
    __shared__ float part[4];
    const int tid  = threadIdx.x;
    const int wave = tid >> 6;
    const int lane = tid & 63;
    const int l15  = lane & 15;
    const int quad = lane >> 4;          // group index (G == 4)
    const int n0   = blockIdx.x * 64 + wave * 16;

    const uint  key_l = keys [quad * NROW + n0 + l15];
    const float xsq_l = xsq_g[quad * NROW + n0 + l15];
    const float sc_l  = __uint_as_float(key_l & 0xFFFFFC00u);
    float lsum = xsq_l - 2.f * sc_l - 1.f;   // dist = x_sq - 2*score - 1

    const float4* __restrict__ cb4 = (const float4*)cbg;
    float4* __restrict__ out4 = (float4*)out;
    const int gbase = quad * (KCB * DIM / 4);
    #pragma unroll
    for (int j = 0; j < 16; ++j) {
        const uint key = (uint)__shfl((int)key_l, (lane & 48) + j);
        const int kidx = (int)(key & 1023u);
        const float4 cw = cb4[gbase + kidx * 16 + l15];
        out4[(size_t)(n0 + j) * 64 + lane] = cw;   // dense 1 KB per wave-instr
    }

    #pragma unroll
    for (int m = 1; m <= 32; m <<= 1) lsum += __shfl_xor(lsum, m);
    if (lane == 0) part[wave] = lsum;
    __syncthreads();
    if (tid == 0)
        atomicAdd(loss, (part[0] + part[1] + part[2] + part[3]) * (1.25f / 8388608.0f));
}

extern "C" void kernel_launch(void* const* d_in, const int* in_sizes, int n_in,
                              void* d_out, int out_size, void* d_ws, size_t ws_size,
                              hipStream_t stream)
{
    const float* latents = (const float*)d_in[0];
    const float* cbg     = (const float*)d_in[1];
    float* out   = (float*)d_out;
    float* lossp = out + 8388608;

    // bf16 latents (16.8 MB) live in the front of d_out; emit overwrites after.
    uint*  lat_bf = (uint*)d_out;
    uint*  keys   = (uint*)d_ws;                         // 512 KB
    float* xsq_g  = (float*)((uint*)d_ws + NTOT);        // 512 KB
    uint*  cb_bf  = (uint*)d_ws + 2 * NTOT;              // 4096*32 words = 512 KB
    float* initv  = (float*)((uint*)d_ws + 2 * NTOT + 131072);  // 16 KB (AFTER cb_bf!)

    vq_prep <<<dim3(528), dim3(256), 0, stream>>>(latents, cbg, lat_bf, cb_bf,
                                                  initv, xsq_g, lossp);
    vq_score<<<dim3(512), dim3(256), 0, stream>>>(lat_bf, cb_bf, initv, keys);
    vq_emit <<<dim3(512), dim3(256), 0, stream>>>(keys, xsq_g, cbg, out, lossp);
}

// Round 3
// 112.983 us; speedup vs baseline: 1.1425x; 1.1425x over previous
//
#include <hip/hip_runtime.h>

#define DIM   64
#define KCB   1024
#define KT2   128    // codewords per LDS tile (8 tiles)
#define NROW  32768

typedef float floatx4 __attribute__((ext_vector_type(4)));
typedef __bf16 bf16x8 __attribute__((ext_vector_type(8)));
typedef unsigned int uint;

union ABu { bf16x8 v; __bf16 h[8]; uint4 u4; };

// ---------------------------------------------------------------------------
// Prep (codebook only now): fp32 codebook -> bf16 rows with 16B-chunk XOR
// swizzle (LDS image) + initv = -0.5*csq - 0.5 (makes every score < 0).
// Latent conversion moved into vq_score (reads fp32 directly). 16 blocks.
// ---------------------------------------------------------------------------
extern "C" __global__ void __launch_bounds__(256)
vq_prep_cb(const float* __restrict__ cbg, uint* __restrict__ cb_bf,
           float* __restrict__ initv, float* __restrict__ loss)
{
    const int k = blockIdx.x * 256 + threadIdx.x;       // 0..4095 codeword row
    const float4* __restrict__ src = (const float4*)cbg + (size_t)k * 16;
    uint* __restrict__ drow = cb_bf + (size_t)k * 32;
    float csq = 0.f;
    #pragma unroll
    for (int c = 0; c < 8; ++c) {
        const float4 f0 = src[c * 2];
        const float4 f1 = src[c * 2 + 1];
        csq += f0.x*f0.x + f0.y*f0.y + f0.z*f0.z + f0.w*f0.w
             + f1.x*f1.x + f1.y*f1.y + f1.z*f1.z + f1.w*f1.w;
        ABu t;
        t.h[0]=(__bf16)f0.x; t.h[1]=(__bf16)f0.y; t.h[2]=(__bf16)f0.z; t.h[3]=(__bf16)f0.w;
        t.h[4]=(__bf16)f1.x; t.h[5]=(__bf16)f1.y; t.h[6]=(__bf16)f1.z; t.h[7]=(__bf16)f1.w;
        const int dc = c ^ (k & 7);       // LDS-bank XOR swizzle baked in
        *(uint4*)&drow[dc * 4] = t.u4;
    }
    initv[k] = -0.5f * csq - 0.5f;
    if (k == 0) *loss = 0.f;
}

// ---------------------------------------------------------------------------
// Fused score+emit: 1024 blocks = chunk(8b,128 rows) | g(2b); 256 thr,
// 32 rows/wave. Reads fp32 latents directly (128B-line coalesced across
// quads), converts to bf16 A-frags in-register, computes xsq on the fly.
// 8x KT2=128 double-buffered codebook tiles (2x16KB) DMA'd via
// global_load_lds, next tile issued before current tile's MFMA (the
// end-of-tile __syncthreads drains it after ~32 MFMA of overlap).
// Argmin accumulates packed keys in regs; epilogue gathers the winning
// fp32 codeword from L2-resident cbg and writes out directly + loss.
// keys/xsq/lat_bf buffers and the emit kernel are GONE.
// LDS 37KB -> 4 blocks/CU; grid 1024 = exactly 4/CU, one pass.
// ---------------------------------------------------------------------------
extern "C" __global__ void __launch_bounds__(256, 4)
vq_score(const float* __restrict__ latents, const uint* __restrict__ cb_bf,
         const float* __restrict__ initv, const float* __restrict__ cbg,
         float* __restrict__ out, float* __restrict__ loss)
{
    __shared__ __attribute__((aligned(16))) uint  cb_lds[2][KT2 * 32]; // 2x16KB
    __shared__ __attribute__((aligned(16))) float iv_lds[KCB];         // 4 KB
    __shared__ float xsq_lds[128];                                     // 512 B
    __shared__ float part[4];

    const int tid  = threadIdx.x;
    const int wave = tid >> 6;
    const int lane = tid & 63;
    const int l15  = lane & 15;
    const int quad = lane >> 4;

    const int bid   = blockIdx.x;
    const int chunk = bid & 255;              // 0..255 (bid%8 spreads XCDs)
    const int g     = bid >> 8;
    const int wRow0 = chunk * 128 + wave * 32;

    const uint* gcb = cb_bf + (size_t)g * (KCB * 32);

    // ---- prologue: DMA tile0 (16KB) + initv (4KB); latent loads overlap ----
    {
        #pragma unroll
        for (int i = 0; i < 4; ++i) {
            const int off = wave * 1024 + i * 256;          // uint words
            __builtin_amdgcn_global_load_lds(
                (const __attribute__((address_space(1))) uint*)(gcb + off + lane * 4),
                (__attribute__((address_space(3))) uint*)&cb_lds[0][off], 16, 0, 0);
        }
        const uint* isrc = (const uint*)(initv + g * KCB) + wave * 256;
        __builtin_amdgcn_global_load_lds(
            (const __attribute__((address_space(1))) uint*)(isrc + lane * 4),
            (__attribute__((address_space(3))) uint*)&iv_lds[wave * 256], 16, 0, 0);
    }

    // ---- A fragments from fp32 latents + xsq, all in-register ----
    // wave instr = 16 rows x 128B contiguous (quads cover the 128B line)
    bf16x8 afrag[2][2];
    float  xp[2];
    const float4* __restrict__ lsrc = (const float4*)latents;
    #pragma unroll
    for (int rt = 0; rt < 2; ++rt) {
        const size_t rb = (size_t)(wRow0 + rt * 16 + l15) * 64 + g * 16
                        + (size_t)quad * 2;
        float s = 0.f;
        #pragma unroll
        for (int ks = 0; ks < 2; ++ks) {
            const float4 f0 = lsrc[rb + ks * 8];
            const float4 f1 = lsrc[rb + ks * 8 + 1];
            s += f0.x*f0.x + f0.y*f0.y + f0.z*f0.z + f0.w*f0.w
               + f1.x*f1.x + f1.y*f1.y + f1.z*f1.z + f1.w*f1.w;
            ABu t;
            t.h[0]=(__bf16)f0.x; t.h[1]=(__bf16)f0.y; t.h[2]=(__bf16)f0.z; t.h[3]=(__bf16)f0.w;
            t.h[4]=(__bf16)f1.x; t.h[5]=(__bf16)f1.y; t.h[6]=(__bf16)f1.z; t.h[7]=(__bf16)f1.w;
            afrag[rt][ks] = t.v;
        }
        s += __shfl_xor(s, 16);
        s += __shfl_xor(s, 32);               // full 64-dim row sum, all quads
        xp[rt] = s;
        if (quad == 0) xsq_lds[wave * 32 + rt * 16 + l15] = s;
    }
    (void)xp;
    __syncthreads();                          // tile0 + iv + xsq ready

    uint best[2][4];
    #pragma unroll
    for (int rt = 0; rt < 2; ++rt)
        #pragma unroll
        for (int r = 0; r < 4; ++r) best[rt][r] = 0xFFFFFFFFu;

    const int o0  = l15 * 32;
    const int sw0 = (quad       ^ (l15 & 7)) << 2;
    const int sw1 = ((quad + 4) ^ (l15 & 7)) << 2;

    #pragma unroll
    for (int tile = 0; tile < 8; ++tile) {
        // issue next tile's DMA first: overlaps the MFMA below
        if (tile < 7) {
            const uint* gsrc = gcb + (tile + 1) * (KT2 * 32);
            #pragma unroll
            for (int i = 0; i < 4; ++i) {
                const int off = wave * 1024 + i * 256;
                __builtin_amdgcn_global_load_lds(
                    (const __attribute__((address_space(1))) uint*)(gsrc + off + lane * 4),
                    (__attribute__((address_space(3))) uint*)&cb_lds[(tile + 1) & 1][off], 16, 0, 0);
            }
        }

        const uint*  bbase0 = &cb_lds[tile & 1][o0 + sw0];
        const uint*  bbase1 = &cb_lds[tile & 1][o0 + sw1];
        const float* ivb    = &iv_lds[tile * KT2 + l15];
        const uint   kcol0  = (uint)(tile * KT2 + l15);

        #pragma unroll 4
        for (int t = 0; t < 8; ++t) {
            const float v = ivb[t * 16];
            ABu b0, b1;
            b0.u4 = *(const uint4*)(bbase0 + t * 512);
            b1.u4 = *(const uint4*)(bbase1 + t * 512);
            const uint kcol = kcol0 + t * 16;
            const floatx4 accb = { v, v, v, v };   // shared C operand (D != C)
            #pragma unroll
            for (int rt = 0; rt < 2; ++rt) {
                floatx4 acc = __builtin_amdgcn_mfma_f32_16x16x32_bf16(afrag[rt][0], b0.v, accb, 0, 0, 0);
                acc = __builtin_amdgcn_mfma_f32_16x16x32_bf16(afrag[rt][1], b1.v, acc, 0, 0, 0);
                // score < 0 -> fp32 bits monotone decreasing; pack idx, min_u32
                #pragma unroll
                for (int r = 0; r < 4; ++r) {
                    const uint key = (__float_as_uint(acc[r]) & 0xFFFFFC00u) | kcol;
                    best[rt][r] = best[rt][r] < key ? best[rt][r] : key;
                }
            }
        }
        __syncthreads();   // drains next-tile DMA (vmcnt) + frees read buffer
    }

    // ---- epilogue: 16-lane argmin reduce -> gather fp32 codeword -> out ----
    float lsum = 0.f;
    const float4* __restrict__ cb4 = (const float4*)cbg + (size_t)g * (KCB * 16);
    float4* __restrict__ out4 = (float4*)out;
    #pragma unroll
    for (int rt = 0; rt < 2; ++rt)
        #pragma unroll
        for (int r = 0; r < 4; ++r) {
            uint kmin = best[rt][r];
            #pragma unroll
            for (int m = 1; m <= 8; m <<= 1) {
                const uint o = (uint)__shfl_xor((int)kmin, m);
                kmin = o < kmin ? o : kmin;
            }
            const int bl   = wave * 32 + rt * 16 + quad * 4 + r;  // block row
            const int n    = chunk * 128 + bl;                    // global row
            const int kidx = (int)(kmin & 1023u);
            // 16 lanes x float4 = 256B contiguous write of this (n,g) slice
            out4[(size_t)n * 64 + g * 16 + l15] = cb4[(size_t)kidx * 16 + l15];
            if (l15 == 0) {
                const float sc = __uint_as_float(kmin & 0xFFFFFC00u);
                lsum += xsq_lds[bl] - 2.f * sc - 1.f;   // exact squared dist
            }
        }
    lsum += __shfl_xor(lsum, 16);
    lsum += __shfl_xor(lsum, 32);             // sum the 4 quad partials
    if (lane == 0) part[wave] = lsum;
    __syncthreads();
    if (tid == 0)
        atomicAdd(loss, (part[0] + part[1] + part[2] + part[3]) * (1.25f / 8388608.0f));
}

extern "C" void kernel_launch(void* const* d_in, const int* in_sizes, int n_in,
                              void* d_out, int out_size, void* d_ws, size_t ws_size,
                              hipStream_t stream)
{
    const float* latents = (const float*)d_in[0];
    const float* cbg     = (const float*)d_in[1];
    float* out   = (float*)d_out;
    float* lossp = out + 8388608;

    uint*  cb_bf = (uint*)d_ws;                          // 512 KB
    float* initv = (float*)((uint*)d_ws + 4096 * 32);    // 16 KB

    vq_prep_cb<<<dim3(16),   dim3(256), 0, stream>>>(cbg, cb_bf, initv, lossp);
    vq_score  <<<dim3(1024), dim3(256), 0, stream>>>(latents, cb_bf, initv,
                                                     cbg, out, lossp);
}